// Round 1
// baseline (717.846 us; speedup 1.0000x reference)
//
#include <hip/hip_runtime.h>
#include <math.h>
#include <float.h>

namespace {

constexpr int B = 256;
constexpr int M = 65536;
constexpr int D = 1024;
constexpr float DECAY_EPS = 1e-8f;
constexpr float DECAY_RATE = 0.999f;

constexpr int MT = 32;    // keys (cols) per block
constexpr int KT = 32;    // k-tile
constexpr int APAD = 260; // A_lds row stride (floats): 256 rows + 4 pad, keeps 16B align
constexpr int BPAD = 36;  // B_lds row stride (floats): 32 cols + 4 pad, keeps 16B align

// ---------------------------------------------------------------------------
// Kernel 1: normalize queries: qn[b][d] = q[b][d] / max(||q_b||, eps)
// ---------------------------------------------------------------------------
__global__ void prep_q_kernel(const float* __restrict__ q, float* __restrict__ qn) {
  const int b = blockIdx.x;
  const int t = threadIdx.x;  // 256 threads, each owns one float4 (4 of 1024 dims)
  float4 v = reinterpret_cast<const float4*>(q + (size_t)b * D)[t];
  float ss = v.x * v.x + v.y * v.y + v.z * v.z + v.w * v.w;
#pragma unroll
  for (int off = 32; off > 0; off >>= 1) ss += __shfl_down(ss, off, 64);
  __shared__ float red[4];
  if ((t & 63) == 0) red[t >> 6] = ss;
  __syncthreads();
  const float tot = red[0] + red[1] + red[2] + red[3];
  const float inv = 1.0f / fmaxf(sqrtf(tot), DECAY_EPS);
  float4 o = make_float4(v.x * inv, v.y * inv, v.z * inv, v.w * inv);
  reinterpret_cast<float4*>(qn + (size_t)b * D)[t] = o;
}

// ---------------------------------------------------------------------------
// Kernel 2: scores[b][j] = (qn_b . k_j) / max(||k_j||,eps)
//                          * 0.999^dt_j * importance_j * log1p(count_j)
// Block: 256 threads, computes all 256 rows x 32 cols. Register tile 8x4.
// ---------------------------------------------------------------------------
__global__ void score_gemm_kernel(const float* __restrict__ qn,
                                  const float* __restrict__ keys,
                                  const float* __restrict__ importance,
                                  const int* __restrict__ atimes,
                                  const int* __restrict__ acnts,
                                  const int* __restrict__ ctime,
                                  float* __restrict__ scores) {
  __shared__ float A[KT][APAD];   // [k][row], transposed so frag reads are b128
  __shared__ float Bs[KT][BPAD];  // [k][col]
  __shared__ float cscale[MT];

  const int t = threadIdx.x;
  const int jb = blockIdx.x * MT;

  // compute mapping: rg in [0,32) covers rows 8*rg..8*rg+7; cg in [0,8) covers cols 4*cg..4*cg+3
  const int rg = t >> 3;
  const int cg = t & 7;
  // staging mapping: bcol in [0,32) key column; bkc in [0,8) k-chunk of 4
  const int bcol = t >> 3;
  const int bkc = t & 7;

  float acc[8][4];
#pragma unroll
  for (int r = 0; r < 8; ++r)
#pragma unroll
    for (int c = 0; c < 4; ++c) acc[r][c] = 0.0f;

  float knorm2 = 0.0f;
  const float* krow = keys + (size_t)(jb + bcol) * D;
  const float* qrowbase = qn + (size_t)t * D;  // thread t stages query row t

  for (int kt = 0; kt < D / KT; ++kt) {
    // issue global loads for this tile
    float4 av[8];
    const float4* qv = reinterpret_cast<const float4*>(qrowbase + kt * KT);
#pragma unroll
    for (int i = 0; i < 8; ++i) av[i] = qv[i];
    float4 bv = *reinterpret_cast<const float4*>(krow + kt * KT + bkc * 4);
    knorm2 += bv.x * bv.x + bv.y * bv.y + bv.z * bv.z + bv.w * bv.w;

    __syncthreads();  // previous tile's compute done before overwrite
    // transposed store of A: per instruction, lanes write contiguous [k][t]
#pragma unroll
    for (int i = 0; i < 8; ++i) {
      A[4 * i + 0][t] = av[i].x;
      A[4 * i + 1][t] = av[i].y;
      A[4 * i + 2][t] = av[i].z;
      A[4 * i + 3][t] = av[i].w;
    }
    Bs[bkc * 4 + 0][bcol] = bv.x;
    Bs[bkc * 4 + 1][bcol] = bv.y;
    Bs[bkc * 4 + 2][bcol] = bv.z;
    Bs[bkc * 4 + 3][bcol] = bv.w;
    __syncthreads();

#pragma unroll 8
    for (int k = 0; k < KT; ++k) {
      float a[8], bb[4];
      *reinterpret_cast<float4*>(&a[0]) = *reinterpret_cast<const float4*>(&A[k][rg * 8]);
      *reinterpret_cast<float4*>(&a[4]) = *reinterpret_cast<const float4*>(&A[k][rg * 8 + 4]);
      *reinterpret_cast<float4*>(&bb[0]) = *reinterpret_cast<const float4*>(&Bs[k][cg * 4]);
#pragma unroll
      for (int r = 0; r < 8; ++r)
#pragma unroll
        for (int c = 0; c < 4; ++c) acc[r][c] = fmaf(a[r], bb[c], acc[r][c]);
    }
  }

  // reduce key-norm^2 across the 8 staging threads of each column (consecutive lanes)
  knorm2 += __shfl_xor(knorm2, 1, 64);
  knorm2 += __shfl_xor(knorm2, 2, 64);
  knorm2 += __shfl_xor(knorm2, 4, 64);
  if (bkc == 0) {
    const int j = jb + bcol;
    const float dt = (float)(ctime[0] - atimes[j]);
    const float mult = powf(DECAY_RATE, dt) * importance[j] * log1pf((float)acnts[j]);
    cscale[bcol] = mult / fmaxf(sqrtf(knorm2), DECAY_EPS);
  }
  __syncthreads();

  float cs[4];
#pragma unroll
  for (int c = 0; c < 4; ++c) cs[c] = cscale[cg * 4 + c];
#pragma unroll
  for (int r = 0; r < 8; ++r) {
    float4 o;
    o.x = acc[r][0] * cs[0];
    o.y = acc[r][1] * cs[1];
    o.z = acc[r][2] * cs[2];
    o.w = acc[r][3] * cs[3];
    *reinterpret_cast<float4*>(&scores[(size_t)(rg * 8 + r) * M + jb + cg * 4]) = o;
  }
}

// ---------------------------------------------------------------------------
// Kernel 3: per-row top-8, softmax, weighted value gather.
// One block (256 threads) per query row.
// ---------------------------------------------------------------------------
__global__ void topk_combine_kernel(const float* __restrict__ scores,
                                    const float* __restrict__ values,
                                    float* __restrict__ out_combined,
                                    float* __restrict__ out_conf) {
  const int b = blockIdx.x;
  const int t = threadIdx.x;
  const float* srow = scores + (size_t)b * M;

  // per-thread sorted (ascending) top-8 of this thread's 256 strided elements
  float s8[8];
  int i8[8];
#pragma unroll
  for (int i = 0; i < 8; ++i) {
    s8[i] = -FLT_MAX;
    i8[i] = 0;
  }
  for (int it = 0; it < M / 256; ++it) {
    const int j = it * 256 + t;
    const float s = srow[j];
    if (s > s8[0]) {
#pragma unroll
      for (int i = 0; i < 8; ++i) {
        if (i == 7 || !(s > s8[i + 1])) {
          s8[i] = s;
          i8[i] = j;
          break;
        }
        s8[i] = s8[i + 1];
        i8[i] = i8[i + 1];
      }
    }
  }

  __shared__ float ls[2048];
  __shared__ int li[2048];
#pragma unroll
  for (int i = 0; i < 8; ++i) {
    ls[t * 8 + i] = s8[i];
    li[t * 8 + i] = i8[i];
  }
  __syncthreads();

  __shared__ float red_s[256];
  __shared__ int red_p[256];
  __shared__ float top_s[8];
  __shared__ int top_i[8];

  for (int r = 0; r < 8; ++r) {
    float ms = -FLT_MAX;
    int mp = 0;
#pragma unroll
    for (int i = 0; i < 8; ++i) {
      const float v = ls[i * 256 + t];
      if (v > ms) {
        ms = v;
        mp = i * 256 + t;
      }
    }
    red_s[t] = ms;
    red_p[t] = mp;
    __syncthreads();
    if (t == 0) {
      float bs = -FLT_MAX;
      int bp = 0;
      for (int i = 0; i < 256; ++i) {
        if (red_s[i] > bs) {
          bs = red_s[i];
          bp = red_p[i];
        }
      }
      top_s[r] = bs;
      top_i[r] = li[bp];
      ls[bp] = -FLT_MAX;  // remove for next round
    }
    __syncthreads();
  }

  // softmax over top-8 (top_s[0] is the max), weights, confidence
  const float mx = top_s[0];
  float w[8];
  float z = 0.0f;
#pragma unroll
  for (int k = 0; k < 8; ++k) {
    w[k] = expf(top_s[k] - mx);
    z += w[k];
  }
  const float invz = 1.0f / z;

  // combine: each thread owns one float4 of the 1024-dim output
  float4 a = make_float4(0.f, 0.f, 0.f, 0.f);
#pragma unroll
  for (int k = 0; k < 8; ++k) {
    const float wk = w[k] * invz;
    const float4 v =
        *reinterpret_cast<const float4*>(values + (size_t)top_i[k] * D + t * 4);
    a.x = fmaf(wk, v.x, a.x);
    a.y = fmaf(wk, v.y, a.y);
    a.z = fmaf(wk, v.z, a.z);
    a.w = fmaf(wk, v.w, a.w);
  }
  *reinterpret_cast<float4*>(out_combined + (size_t)b * D + t * 4) = a;
  if (t == 0) out_conf[b] = w[0] * invz;  // max weight = weight of max score
}

}  // namespace

extern "C" void kernel_launch(void* const* d_in, const int* in_sizes, int n_in,
                              void* d_out, int out_size, void* d_ws, size_t ws_size,
                              hipStream_t stream) {
  const float* query = (const float*)d_in[0];
  const float* keys = (const float*)d_in[1];
  const float* values = (const float*)d_in[2];
  const float* importance = (const float*)d_in[3];
  const int* atimes = (const int*)d_in[4];
  const int* acnts = (const int*)d_in[5];
  const int* ctime = (const int*)d_in[6];
  // d_in[7] = top_k, fixed at 8 per setup_inputs

  float* out = (float*)d_out;                 // combined [B*D] then confidence [B]
  float* qn = (float*)d_ws;                   // B*D floats
  float* scores = qn + (size_t)B * D;         // B*M floats (64 MB)

  prep_q_kernel<<<B, 256, 0, stream>>>(query, qn);
  score_gemm_kernel<<<M / MT, 256, 0, stream>>>(qn, keys, importance, atimes,
                                                acnts, ctime, scores);
  topk_combine_kernel<<<B, 256, 0, stream>>>(scores, values, out,
                                             out + (size_t)B * D);
}

// Round 2
// 328.384 us; speedup vs baseline: 2.1860x; 2.1860x over previous
//
#include <hip/hip_runtime.h>
#include <math.h>
#include <float.h>

typedef __attribute__((ext_vector_type(8))) short short8;
typedef __attribute__((ext_vector_type(4))) float f32x4;

namespace {

constexpr int B = 256;
constexpr int M = 65536;
constexpr int D = 1024;
constexpr float DECAY_EPS = 1e-8f;
constexpr float DECAY_RATE = 0.999f;

constexpr int BN = 64;          // keys per block
constexpr int BK = 32;          // k per step (one MFMA deep)
constexpr int KSTEPS = D / BK;  // 32

__device__ inline ushort f2bf(float f) {
  union { float f; unsigned u; } v; v.f = f;
  unsigned r = v.u + 0x7fffu + ((v.u >> 16) & 1u);  // RNE
  return (ushort)(r >> 16);
}

// ---------------------------------------------------------------------------
// Kernel 1: normalize queries, emit bf16 in MFMA A-fragment order:
// qnf element ((kt*16 + m_tile)*512 + lane*8 + j) holds
//   qn[m_tile*16 + (lane&15)][kt*32 + (lane>>4)*8 + j]
// so a wave's A-fragment load is one coalesced 16B/lane global load.
// ---------------------------------------------------------------------------
__global__ void prep_q_kernel(const float* __restrict__ q, ushort* __restrict__ qnf) {
  const int r = blockIdx.x;
  const int t = threadIdx.x;  // 256 threads x float4
  float4 v = reinterpret_cast<const float4*>(q + (size_t)r * D)[t];
  float ss = v.x * v.x + v.y * v.y + v.z * v.z + v.w * v.w;
#pragma unroll
  for (int off = 32; off; off >>= 1) ss += __shfl_down(ss, off, 64);
  __shared__ float red[4];
  if ((t & 63) == 0) red[t >> 6] = ss;
  __syncthreads();
  const float inv = 1.0f / fmaxf(sqrtf(red[0] + red[1] + red[2] + red[3]), DECAY_EPS);
  ushort4 o;
  o.x = f2bf(v.x * inv); o.y = f2bf(v.y * inv);
  o.z = f2bf(v.z * inv); o.w = f2bf(v.w * inv);
  const int k0 = t * 4;
  const int kt = k0 >> 5;
  const int lane_slot = (r & 15) + 16 * ((k0 & 31) >> 3);
  const int j0 = k0 & 7;  // 0 or 4
  *reinterpret_cast<ushort4*>(qnf + (size_t)(kt * 16 + (r >> 4)) * 512 + lane_slot * 8 + j0) = o;
}

// ---------------------------------------------------------------------------
// Kernel 2: scores[b][j] = (qn_b . k_j)/max(||k_j||,eps) * mult_j  via bf16 MFMA.
// Block: 256 thr (4 waves), BM=256 (all rows) x BN=64 keys, BK=32.
// Wave w owns rows w*64..w*64+63 (m_tiles w*4+f), all 64 cols (n-frags 0..3).
// A: direct coalesced global loads from qnf (L2-resident).
// B: keys fp32 -> reg -> cvt bf16 -> swizzled double-buffered LDS.
// ---------------------------------------------------------------------------
__global__ __launch_bounds__(256) void score_gemm_kernel(
    const ushort* __restrict__ qnf, const float* __restrict__ keys,
    const float* __restrict__ importance, const int* __restrict__ atimes,
    const int* __restrict__ acnts, const int* __restrict__ ctime,
    float* __restrict__ scores) {
  __shared__ alignas(16) ushort Bs[2][BN * BK];
  __shared__ float cscale[BN];

  const int t = threadIdx.x;
  const int lane = t & 63;
  const int w = t >> 6;
  const int jb = blockIdx.x * BN;

  // staging: thread t stages key row rw, k-chunk cw (8 floats)
  const int rw = t >> 2;
  const int cw = t & 3;
  const float* kptr = keys + (size_t)(jb + rw) * D + cw * 8;
  // swizzled LDS elem offset: slot = cw ^ ((rw>>1)&3), 8 bf16 per slot
  const int woff = rw * BK + ((cw ^ ((rw >> 1) & 3)) * 8);

  f32x4 acc[4][4];
#pragma unroll
  for (int f = 0; f < 4; ++f)
#pragma unroll
    for (int n = 0; n < 4; ++n) acc[f][n] = (f32x4)(0.0f);

  float kn2 = 0.0f;

  // prologue: stage step 0
  {
    float4 v0 = *reinterpret_cast<const float4*>(kptr);
    float4 v1 = *reinterpret_cast<const float4*>(kptr + 4);
    kn2 += v0.x * v0.x + v0.y * v0.y + v0.z * v0.z + v0.w * v0.w;
    kn2 += v1.x * v1.x + v1.y * v1.y + v1.z * v1.z + v1.w * v1.w;
    short8 pk;
    pk[0] = (short)f2bf(v0.x); pk[1] = (short)f2bf(v0.y);
    pk[2] = (short)f2bf(v0.z); pk[3] = (short)f2bf(v0.w);
    pk[4] = (short)f2bf(v1.x); pk[5] = (short)f2bf(v1.y);
    pk[6] = (short)f2bf(v1.z); pk[7] = (short)f2bf(v1.w);
    *reinterpret_cast<short8*>(&Bs[0][woff]) = pk;
  }
  __syncthreads();

  // B-frag read offsets (swizzle matches write): lane reads row nf*16+(lane&15),
  // k-slot (lane>>4) ^ ((row>>1)&3)
  int roff[4];
#pragma unroll
  for (int nf = 0; nf < 4; ++nf) {
    const int row = nf * 16 + (lane & 15);
    roff[nf] = row * BK + (((lane >> 4) ^ ((row >> 1) & 3)) * 8);
  }

  for (int kt = 0; kt < KSTEPS; ++kt) {
    const int cur = kt & 1;
    float4 nv0, nv1;
    if (kt + 1 < KSTEPS) {
      nv0 = *reinterpret_cast<const float4*>(kptr + (kt + 1) * BK);
      nv1 = *reinterpret_cast<const float4*>(kptr + (kt + 1) * BK + 4);
    }
    // A fragments: coalesced 16B/lane from qnf (L2)
    short8 a[4];
    const short8* ap = reinterpret_cast<const short8*>(qnf) + (size_t)(kt * 16 + w * 4) * 64 + lane;
#pragma unroll
    for (int f = 0; f < 4; ++f) a[f] = ap[f * 64];
    // B fragments from LDS
    short8 bb[4];
#pragma unroll
    for (int nf = 0; nf < 4; ++nf)
      bb[nf] = *reinterpret_cast<const short8*>(&Bs[cur][roff[nf]]);
#pragma unroll
    for (int f = 0; f < 4; ++f)
#pragma unroll
      for (int nf = 0; nf < 4; ++nf)
        acc[f][nf] = __builtin_amdgcn_mfma_f32_16x16x32_bf16(a[f], bb[nf], acc[f][nf], 0, 0, 0);
    if (kt + 1 < KSTEPS) {
      kn2 += nv0.x * nv0.x + nv0.y * nv0.y + nv0.z * nv0.z + nv0.w * nv0.w;
      kn2 += nv1.x * nv1.x + nv1.y * nv1.y + nv1.z * nv1.z + nv1.w * nv1.w;
      short8 pk;
      pk[0] = (short)f2bf(nv0.x); pk[1] = (short)f2bf(nv0.y);
      pk[2] = (short)f2bf(nv0.z); pk[3] = (short)f2bf(nv0.w);
      pk[4] = (short)f2bf(nv1.x); pk[5] = (short)f2bf(nv1.y);
      pk[6] = (short)f2bf(nv1.z); pk[7] = (short)f2bf(nv1.w);
      *reinterpret_cast<short8*>(&Bs[cur ^ 1][woff]) = pk;
    }
    __syncthreads();
  }

  // key norm^2: reduce over the 4 staging threads of row rw (lanes differ in bits 0..1)
  kn2 += __shfl_xor(kn2, 1, 64);
  kn2 += __shfl_xor(kn2, 2, 64);
  if (cw == 0) {
    const int j = jb + rw;
    const float dt = (float)(ctime[0] - atimes[j]);
    const float mult = powf(DECAY_RATE, dt) * importance[j] * log1pf((float)acnts[j]);
    cscale[rw] = mult / fmaxf(sqrtf(kn2), DECAY_EPS);
  }
  __syncthreads();

  // epilogue: C/D layout col=lane&15, row=(lane>>4)*4+reg  [m89-verified]
#pragma unroll
  for (int f = 0; f < 4; ++f) {
    const int row0 = (w * 4 + f) * 16 + ((lane >> 4) << 2);
#pragma unroll
    for (int nf = 0; nf < 4; ++nf) {
      const int col = nf * 16 + (lane & 15);
      const float cs = cscale[col];
#pragma unroll
      for (int rr = 0; rr < 4; ++rr)
        scores[(size_t)(row0 + rr) * M + jb + col] = acc[f][nf][rr] * cs;
    }
  }
}

// ---------------------------------------------------------------------------
// Kernel 3: per-row approx top-16 -> exact fp32 rescore -> top-8 -> softmax
// -> weighted gather. One block (512 thr) per query row.
// ---------------------------------------------------------------------------
__global__ __launch_bounds__(512) void topk_kernel(
    const float* __restrict__ scores, const float* __restrict__ query,
    const float* __restrict__ keys, const float* __restrict__ values,
    const float* __restrict__ importance, const int* __restrict__ atimes,
    const int* __restrict__ acnts, const int* __restrict__ ctime,
    float* __restrict__ outc, float* __restrict__ conf) {
  const int b = blockIdx.x;
  const int t = threadIdx.x;
  const int lane = t & 63, w = t >> 6;

  // phase 1: per-thread top-8 over 32 float4 (batched x4 for MLP)
  float s8[8];
  int i8[8];
#pragma unroll
  for (int i = 0; i < 8; ++i) { s8[i] = -FLT_MAX; i8[i] = 0; }
  const float4* srow4 = reinterpret_cast<const float4*>(scores + (size_t)b * M);

  auto insert = [&](float s, int j) {
    if (s > s8[0]) {
#pragma unroll
      for (int i = 0; i < 8; ++i) {
        if (i == 7 || !(s > s8[i + 1])) { s8[i] = s; i8[i] = j; break; }
        s8[i] = s8[i + 1]; i8[i] = i8[i + 1];
      }
    }
  };

  for (int it = 0; it < 8; ++it) {
    float4 vv[4];
    int j4[4];
#pragma unroll
    for (int u = 0; u < 4; ++u) {
      j4[u] = (it * 4 + u) * 512 + t;
      vv[u] = srow4[j4[u]];
    }
#pragma unroll
    for (int u = 0; u < 4; ++u) {
      insert(vv[u].x, j4[u] * 4 + 0);
      insert(vv[u].y, j4[u] * 4 + 1);
      insert(vv[u].z, j4[u] * 4 + 2);
      insert(vv[u].w, j4[u] * 4 + 3);
    }
  }

  __shared__ float ls[4096];
  __shared__ int li[4096];
#pragma unroll
  for (int i = 0; i < 8; ++i) { ls[t * 8 + i] = s8[i]; li[t * 8 + i] = i8[i]; }
  __syncthreads();

  // phase 2: extract global approx top-16
  __shared__ float rs_[8];
  __shared__ int rp_[8];
  __shared__ int cidx[16];
  for (int r = 0; r < 16; ++r) {
    float ms = -FLT_MAX;
    int mp = 0;
#pragma unroll
    for (int i = 0; i < 8; ++i) {
      const float v = ls[i * 512 + t];
      if (v > ms) { ms = v; mp = i * 512 + t; }
    }
#pragma unroll
    for (int off = 32; off; off >>= 1) {
      const float ov = __shfl_xor(ms, off, 64);
      const int op = __shfl_xor(mp, off, 64);
      if (ov > ms) { ms = ov; mp = op; }
    }
    if (lane == 0) { rs_[w] = ms; rp_[w] = mp; }
    __syncthreads();
    if (t == 0) {
      float bs = -FLT_MAX;
      int bp = 0;
      for (int i = 0; i < 8; ++i)
        if (rs_[i] > bs) { bs = rs_[i]; bp = rp_[i]; }
      cidx[r] = li[bp];
      ls[bp] = -FLT_MAX;
    }
    __syncthreads();
  }

  // phase 3: exact fp32 rescore of the 16 candidates
  __shared__ float wredA[8], wredB[8];
  __shared__ float smult[16], sc[16];
  const float2 qv = *reinterpret_cast<const float2*>(query + (size_t)b * D + 2 * t);
  {
    float ssq = qv.x * qv.x + qv.y * qv.y;
#pragma unroll
    for (int off = 32; off; off >>= 1) ssq += __shfl_xor(ssq, off, 64);
    if (lane == 0) wredA[w] = ssq;
  }
  if (t < 16) {
    const int j = cidx[t];
    const float dtv = (float)(ctime[0] - atimes[j]);
    smult[t] = powf(DECAY_RATE, dtv) * importance[j] * log1pf((float)acnts[j]);
  }
  __syncthreads();
  float qn2 = 0.0f;
#pragma unroll
  for (int i = 0; i < 8; ++i) qn2 += wredA[i];
  const float qdn = fmaxf(sqrtf(qn2), DECAY_EPS);
  __syncthreads();  // everyone done reading wredA before it is reused

  for (int c = 0; c < 16; ++c) {
    const float2 kv = *reinterpret_cast<const float2*>(keys + (size_t)cidx[c] * D + 2 * t);
    float dd = qv.x * kv.x + qv.y * kv.y;
    float nn = kv.x * kv.x + kv.y * kv.y;
#pragma unroll
    for (int off = 32; off; off >>= 1) {
      dd += __shfl_xor(dd, off, 64);
      nn += __shfl_xor(nn, off, 64);
    }
    if (lane == 0) { wredA[w] = dd; wredB[w] = nn; }
    __syncthreads();
    if (t == 0) {
      float dsum = 0.0f, nsum = 0.0f;
      for (int i = 0; i < 8; ++i) { dsum += wredA[i]; nsum += wredB[i]; }
      sc[c] = dsum / (qdn * fmaxf(sqrtf(nsum), DECAY_EPS)) * smult[c];
    }
    __syncthreads();
  }

  // phase 4: exact top-8 of 16, softmax, weights
  __shared__ float w8[8];
  __shared__ int g8[8];
  __shared__ float confv;
  if (t == 0) {
    float best[8];
    int bi[8];
    unsigned taken = 0;
    for (int r = 0; r < 8; ++r) {
      float bs = -FLT_MAX;
      int bc = 0;
      for (int c = 0; c < 16; ++c)
        if (!((taken >> c) & 1u) && sc[c] > bs) { bs = sc[c]; bc = c; }
      taken |= 1u << bc;
      best[r] = bs;
      bi[r] = bc;
    }
    const float mx = best[0];
    float z = 0.0f;
    float e[8];
    for (int r = 0; r < 8; ++r) { e[r] = expf(best[r] - mx); z += e[r]; }
    const float invz = 1.0f / z;
    for (int r = 0; r < 8; ++r) { w8[r] = e[r] * invz; g8[r] = cidx[bi[r]]; }
    confv = w8[0];
  }
  __syncthreads();

  // phase 5: combine
  float2 acc = make_float2(0.0f, 0.0f);
#pragma unroll
  for (int k = 0; k < 8; ++k) {
    const float wk = w8[k];
    const float2 v = *reinterpret_cast<const float2*>(values + (size_t)g8[k] * D + 2 * t);
    acc.x = fmaf(wk, v.x, acc.x);
    acc.y = fmaf(wk, v.y, acc.y);
  }
  *reinterpret_cast<float2*>(outc + (size_t)b * D + 2 * t) = acc;
  if (t == 0) conf[b] = confv;
}

}  // namespace

extern "C" void kernel_launch(void* const* d_in, const int* in_sizes, int n_in,
                              void* d_out, int out_size, void* d_ws, size_t ws_size,
                              hipStream_t stream) {
  const float* query = (const float*)d_in[0];
  const float* keys = (const float*)d_in[1];
  const float* values = (const float*)d_in[2];
  const float* importance = (const float*)d_in[3];
  const int* atimes = (const int*)d_in[4];
  const int* acnts = (const int*)d_in[5];
  const int* ctime = (const int*)d_in[6];

  float* out = (float*)d_out;  // combined [B*D] then confidence [B]
  ushort* qnf = (ushort*)d_ws;                          // 256*1024 bf16 = 512 KB
  float* scores = (float*)((char*)d_ws + (size_t)B * D * sizeof(ushort));  // B*M f32

  prep_q_kernel<<<B, 256, 0, stream>>>(query, qnf);
  score_gemm_kernel<<<M / BN, 256, 0, stream>>>(qnf, keys, importance, atimes,
                                                acnts, ctime, scores);
  topk_kernel<<<B, 512, 0, stream>>>(scores, query, keys, values, importance,
                                     atimes, acnts, ctime, out, out + (size_t)B * D);
}

// Round 3
// 171.329 us; speedup vs baseline: 4.1899x; 1.9167x over previous
//
#include <hip/hip_runtime.h>
#include <hip/hip_bf16.h>
#include <math.h>
#include <float.h>

typedef __attribute__((ext_vector_type(8))) short short8;
typedef __attribute__((ext_vector_type(4))) float f32x4;

namespace {

constexpr int B = 256;
constexpr int M = 65536;
constexpr int D = 1024;
constexpr float DECAY_EPS = 1e-8f;
constexpr float DECAY_RATE = 0.999f;

constexpr int BN = 64;          // keys per GEMM block
constexpr int BK = 32;          // k per step
constexpr int KSTEPS = D / BK;  // 32

constexpr int CHUNKS = 8;           // top-k chunks per row
constexpr int CHUNK = M / CHUNKS;   // 8192
constexpr int NCAND = CHUNKS * 8;   // 64 candidates per row

__device__ inline ushort f2bf(float f) {
  union { __hip_bfloat16 h; ushort u; } v;
  v.h = __float2bfloat16(f);
  return v.u;
}

// ---------------------------------------------------------------------------
// Kernel 1: normalize queries, emit bf16 in MFMA A-fragment order.
// ---------------------------------------------------------------------------
__global__ void prep_q_kernel(const float* __restrict__ q, ushort* __restrict__ qnf) {
  const int r = blockIdx.x;
  const int t = threadIdx.x;  // 256 threads x float4
  float4 v = reinterpret_cast<const float4*>(q + (size_t)r * D)[t];
  float ss = v.x * v.x + v.y * v.y + v.z * v.z + v.w * v.w;
#pragma unroll
  for (int off = 32; off; off >>= 1) ss += __shfl_down(ss, off, 64);
  __shared__ float red[4];
  if ((t & 63) == 0) red[t >> 6] = ss;
  __syncthreads();
  const float inv = 1.0f / fmaxf(sqrtf(red[0] + red[1] + red[2] + red[3]), DECAY_EPS);
  ushort4 o;
  o.x = f2bf(v.x * inv); o.y = f2bf(v.y * inv);
  o.z = f2bf(v.z * inv); o.w = f2bf(v.w * inv);
  const int k0 = t * 4;
  const int kt = k0 >> 5;
  const int lane_slot = (r & 15) + 16 * ((k0 & 31) >> 3);
  const int j0 = k0 & 7;  // 0 or 4
  *reinterpret_cast<ushort4*>(qnf + (size_t)(kt * 16 + (r >> 4)) * 512 + lane_slot * 8 + j0) = o;
}

// ---------------------------------------------------------------------------
// Kernel 2: bf16-MFMA scores (approx; exact rescore happens in stage B).
// ---------------------------------------------------------------------------
__global__ __launch_bounds__(256) void score_gemm_kernel(
    const ushort* __restrict__ qnf, const float* __restrict__ keys,
    const float* __restrict__ importance, const int* __restrict__ atimes,
    const int* __restrict__ acnts, const int* __restrict__ ctime,
    float* __restrict__ scores) {
  __shared__ alignas(16) ushort Bs[2][BN * BK];
  __shared__ float cscale[BN];

  const int t = threadIdx.x;
  const int lane = t & 63;
  const int w = t >> 6;
  const int jb = blockIdx.x * BN;

  const int rw = t >> 2;
  const int cw = t & 3;
  const float* kptr = keys + (size_t)(jb + rw) * D + cw * 8;
  const int woff = rw * BK + ((cw ^ ((rw >> 1) & 3)) * 8);

  f32x4 acc[4][4];
#pragma unroll
  for (int f = 0; f < 4; ++f)
#pragma unroll
    for (int n = 0; n < 4; ++n) acc[f][n] = (f32x4)(0.0f);

  float kn2 = 0.0f;

  {
    float4 v0 = *reinterpret_cast<const float4*>(kptr);
    float4 v1 = *reinterpret_cast<const float4*>(kptr + 4);
    kn2 += v0.x * v0.x + v0.y * v0.y + v0.z * v0.z + v0.w * v0.w;
    kn2 += v1.x * v1.x + v1.y * v1.y + v1.z * v1.z + v1.w * v1.w;
    short8 pk;
    pk[0] = (short)f2bf(v0.x); pk[1] = (short)f2bf(v0.y);
    pk[2] = (short)f2bf(v0.z); pk[3] = (short)f2bf(v0.w);
    pk[4] = (short)f2bf(v1.x); pk[5] = (short)f2bf(v1.y);
    pk[6] = (short)f2bf(v1.z); pk[7] = (short)f2bf(v1.w);
    *reinterpret_cast<short8*>(&Bs[0][woff]) = pk;
  }
  __syncthreads();

  int roff[4];
#pragma unroll
  for (int nf = 0; nf < 4; ++nf) {
    const int row = nf * 16 + (lane & 15);
    roff[nf] = row * BK + (((lane >> 4) ^ ((row >> 1) & 3)) * 8);
  }

  for (int kt = 0; kt < KSTEPS; ++kt) {
    const int cur = kt & 1;
    float4 nv0, nv1;
    if (kt + 1 < KSTEPS) {
      nv0 = *reinterpret_cast<const float4*>(kptr + (kt + 1) * BK);
      nv1 = *reinterpret_cast<const float4*>(kptr + (kt + 1) * BK + 4);
    }
    short8 a[4];
    const short8* ap = reinterpret_cast<const short8*>(qnf) + (size_t)(kt * 16 + w * 4) * 64 + lane;
#pragma unroll
    for (int f = 0; f < 4; ++f) a[f] = ap[f * 64];
    short8 bb[4];
#pragma unroll
    for (int nf = 0; nf < 4; ++nf)
      bb[nf] = *reinterpret_cast<const short8*>(&Bs[cur][roff[nf]]);
#pragma unroll
    for (int f = 0; f < 4; ++f)
#pragma unroll
      for (int nf = 0; nf < 4; ++nf)
        acc[f][nf] = __builtin_amdgcn_mfma_f32_16x16x32_bf16(a[f], bb[nf], acc[f][nf], 0, 0, 0);
    if (kt + 1 < KSTEPS) {
      kn2 += nv0.x * nv0.x + nv0.y * nv0.y + nv0.z * nv0.z + nv0.w * nv0.w;
      kn2 += nv1.x * nv1.x + nv1.y * nv1.y + nv1.z * nv1.z + nv1.w * nv1.w;
      short8 pk;
      pk[0] = (short)f2bf(nv0.x); pk[1] = (short)f2bf(nv0.y);
      pk[2] = (short)f2bf(nv0.z); pk[3] = (short)f2bf(nv0.w);
      pk[4] = (short)f2bf(nv1.x); pk[5] = (short)f2bf(nv1.y);
      pk[6] = (short)f2bf(nv1.z); pk[7] = (short)f2bf(nv1.w);
      *reinterpret_cast<short8*>(&Bs[cur ^ 1][woff]) = pk;
    }
    __syncthreads();
  }

  kn2 += __shfl_xor(kn2, 1, 64);
  kn2 += __shfl_xor(kn2, 2, 64);
  if (cw == 0) {
    const int j = jb + rw;
    const float dt = (float)(ctime[0] - atimes[j]);
    const float mult = powf(DECAY_RATE, dt) * importance[j] * log1pf((float)acnts[j]);
    cscale[rw] = mult / fmaxf(sqrtf(kn2), DECAY_EPS);
  }
  __syncthreads();

#pragma unroll
  for (int f = 0; f < 4; ++f) {
    const int row0 = (w * 4 + f) * 16 + ((lane >> 4) << 2);
#pragma unroll
    for (int nf = 0; nf < 4; ++nf) {
      const int col = nf * 16 + (lane & 15);
      const float cs = cscale[col];
#pragma unroll
      for (int rr = 0; rr < 4; ++rr)
        scores[(size_t)(row0 + rr) * M + jb + col] = acc[f][nf][rr] * cs;
    }
  }
}

// ---------------------------------------------------------------------------
// Kernel 3 (stage A): per (row, chunk) top-8 indices. Branch-free insertion,
// all static indexing (registers, NOT scratch).
// ---------------------------------------------------------------------------
__global__ __launch_bounds__(256) void topk_partial_kernel(
    const float* __restrict__ scores, int* __restrict__ cand_i) {
  const int b = blockIdx.y;
  const int c = blockIdx.x;
  const int t = threadIdx.x;
  const int lane = t & 63, w = t >> 6;
  const float4* base4 = reinterpret_cast<const float4*>(scores + (size_t)b * M + (size_t)c * CHUNK);

  float s8[8];
  int i8[8];
#pragma unroll
  for (int i = 0; i < 8; ++i) { s8[i] = -FLT_MAX; i8[i] = 0; }

  auto ins = [&](float x, int j) {
    if (x > s8[0]) {
#pragma unroll
      for (int i = 0; i < 8; ++i) {
        const bool up = (i < 7) && (x > s8[i + 1]);
        const float ks = (x > s8[i]) ? x : s8[i];
        const int ki = (x > s8[i]) ? j : i8[i];
        s8[i] = up ? s8[i + 1] : ks;
        i8[i] = up ? i8[i + 1] : ki;
      }
    }
  };

  const int jbase = c * CHUNK;
  for (int it = 0; it < CHUNK / (256 * 4); ++it) {  // 8 iters
    const int slot = it * 256 + t;
    const float4 v = base4[slot];
    const int j0 = jbase + slot * 4;
    ins(v.x, j0 + 0);
    ins(v.y, j0 + 1);
    ins(v.z, j0 + 2);
    ins(v.w, j0 + 3);
  }

  __shared__ float ls[2048];
  __shared__ int li[2048];
#pragma unroll
  for (int i = 0; i < 8; ++i) { ls[t * 8 + i] = s8[i]; li[t * 8 + i] = i8[i]; }
  __syncthreads();

  __shared__ float rs4[4];
  __shared__ int rp4[4];
  for (int r = 0; r < 8; ++r) {
    float ms = -FLT_MAX;
    int mp = 0;
#pragma unroll
    for (int i = 0; i < 8; ++i) {
      const float v = ls[i * 256 + t];
      if (v > ms) { ms = v; mp = i * 256 + t; }
    }
#pragma unroll
    for (int off = 32; off; off >>= 1) {
      const float ov = __shfl_xor(ms, off, 64);
      const int op = __shfl_xor(mp, off, 64);
      if (ov > ms) { ms = ov; mp = op; }
    }
    if (lane == 0) { rs4[w] = ms; rp4[w] = mp; }
    __syncthreads();
    if (t == 0) {
      float bs = -FLT_MAX;
      int bp = 0;
#pragma unroll
      for (int i = 0; i < 4; ++i)
        if (rs4[i] > bs) { bs = rs4[i]; bp = rp4[i]; }
      cand_i[((size_t)b * CHUNKS + c) * 8 + r] = li[bp];
      ls[bp] = -FLT_MAX;
    }
    __syncthreads();
  }
}

// ---------------------------------------------------------------------------
// Kernel 4 (stage B): exact fp32 rescore of 64 candidates, top-8, softmax,
// weighted value gather. One block (512 thr = 8 waves) per row.
// ---------------------------------------------------------------------------
__global__ __launch_bounds__(512) void rescore_kernel(
    const int* __restrict__ cand_i, const float* __restrict__ query,
    const float* __restrict__ keys, const float* __restrict__ values,
    const float* __restrict__ importance, const int* __restrict__ atimes,
    const int* __restrict__ acnts, const int* __restrict__ ctime,
    float* __restrict__ outc, float* __restrict__ conf) {
  const int b = blockIdx.x;
  const int t = threadIdx.x;
  const int lane = t & 63, w = t >> 6;

  // each lane owns 16 contiguous dims of the row (wave covers all 1024)
  const float4* qv4 = reinterpret_cast<const float4*>(query + (size_t)b * D + lane * 16);
  float4 q0 = qv4[0], q1 = qv4[1], q2 = qv4[2], q3 = qv4[3];
  float ssq = q0.x * q0.x + q0.y * q0.y + q0.z * q0.z + q0.w * q0.w
            + q1.x * q1.x + q1.y * q1.y + q1.z * q1.z + q1.w * q1.w
            + q2.x * q2.x + q2.y * q2.y + q2.z * q2.z + q2.w * q2.w
            + q3.x * q3.x + q3.y * q3.y + q3.z * q3.z + q3.w * q3.w;
#pragma unroll
  for (int off = 32; off; off >>= 1) ssq += __shfl_xor(ssq, off, 64);
  const float qdn = fmaxf(sqrtf(ssq), DECAY_EPS);
  const int ct = ctime[0];

  __shared__ float sc[NCAND];
  __shared__ int sidx[NCAND];

  for (int u = 0; u < 8; ++u) {
    const int c = w * 8 + u;
    const int j = cand_i[(size_t)b * NCAND + c];
    const float4* kv4 = reinterpret_cast<const float4*>(keys + (size_t)j * D + lane * 16);
    const float4 k0 = kv4[0], k1 = kv4[1], k2 = kv4[2], k3 = kv4[3];
    float dd = q0.x * k0.x + q0.y * k0.y + q0.z * k0.z + q0.w * k0.w
             + q1.x * k1.x + q1.y * k1.y + q1.z * k1.z + q1.w * k1.w
             + q2.x * k2.x + q2.y * k2.y + q2.z * k2.z + q2.w * k2.w
             + q3.x * k3.x + q3.y * k3.y + q3.z * k3.z + q3.w * k3.w;
    float nn = k0.x * k0.x + k0.y * k0.y + k0.z * k0.z + k0.w * k0.w
             + k1.x * k1.x + k1.y * k1.y + k1.z * k1.z + k1.w * k1.w
             + k2.x * k2.x + k2.y * k2.y + k2.z * k2.z + k2.w * k2.w
             + k3.x * k3.x + k3.y * k3.y + k3.z * k3.z + k3.w * k3.w;
#pragma unroll
    for (int off = 32; off; off >>= 1) {
      dd += __shfl_xor(dd, off, 64);
      nn += __shfl_xor(nn, off, 64);
    }
    if (lane == 0) {
      const float dtv = (float)(ct - atimes[j]);
      const float mult = powf(DECAY_RATE, dtv) * importance[j] * log1pf((float)acnts[j]);
      sc[c] = dd / (qdn * fmaxf(sqrtf(nn), DECAY_EPS)) * mult;
      sidx[c] = j;
    }
  }
  __syncthreads();

  __shared__ float w8s[8];
  __shared__ int g8[8];
  __shared__ float confv;
  __shared__ float tls[8];
  __shared__ int tli[8];
  if (w == 0) {
    float myv = sc[lane];  // lanes 0..63 <-> candidates 0..63
    for (int r = 0; r < 8; ++r) {
      float m = myv;
      int mi = lane;
#pragma unroll
      for (int off = 32; off; off >>= 1) {
        const float ov = __shfl_xor(m, off, 64);
        const int oi = __shfl_xor(mi, off, 64);
        if (ov > m || (ov == m && oi < mi)) { m = ov; mi = oi; }
      }
      if (lane == 0) { tls[r] = m; tli[r] = mi; }
      if (lane == mi) myv = -FLT_MAX;
    }
    if (lane == 0) {
      const float mx = tls[0];
      float e[8];
      float z = 0.0f;
#pragma unroll
      for (int r = 0; r < 8; ++r) { e[r] = expf(tls[r] - mx); z += e[r]; }
      const float invz = 1.0f / z;
#pragma unroll
      for (int r = 0; r < 8; ++r) { w8s[r] = e[r] * invz; g8[r] = sidx[tli[r]]; }
      confv = w8s[0];
    }
  }
  __syncthreads();

  float2 acc = make_float2(0.0f, 0.0f);
#pragma unroll
  for (int k = 0; k < 8; ++k) {
    const float wk = w8s[k];
    const float2 v = *reinterpret_cast<const float2*>(values + (size_t)g8[k] * D + 2 * t);
    acc.x = fmaf(wk, v.x, acc.x);
    acc.y = fmaf(wk, v.y, acc.y);
  }
  *reinterpret_cast<float2*>(outc + (size_t)b * D + 2 * t) = acc;
  if (t == 0) conf[b] = confv;
}

}  // namespace

extern "C" void kernel_launch(void* const* d_in, const int* in_sizes, int n_in,
                              void* d_out, int out_size, void* d_ws, size_t ws_size,
                              hipStream_t stream) {
  const float* query = (const float*)d_in[0];
  const float* keys = (const float*)d_in[1];
  const float* values = (const float*)d_in[2];
  const float* importance = (const float*)d_in[3];
  const int* atimes = (const int*)d_in[4];
  const int* acnts = (const int*)d_in[5];
  const int* ctime = (const int*)d_in[6];

  float* out = (float*)d_out;  // combined [B*D] then confidence [B]
  ushort* qnf = (ushort*)d_ws;                                        // 512 KB
  float* scores = (float*)((char*)d_ws + (size_t)B * D * sizeof(ushort));  // 64 MB
  int* cand = (int*)(scores + (size_t)B * M);                         // 64 KB

  prep_q_kernel<<<B, 256, 0, stream>>>(query, qnf);
  score_gemm_kernel<<<M / BN, 256, 0, stream>>>(qnf, keys, importance, atimes,
                                                acnts, ctime, scores);
  dim3 gA(CHUNKS, B);
  topk_partial_kernel<<<gA, 256, 0, stream>>>(scores, cand);
  rescore_kernel<<<B, 512, 0, stream>>>(cand, query, keys, values, importance,
                                        atimes, acnts, ctime, out, out + (size_t)B * D);
}

// Round 4
// 150.346 us; speedup vs baseline: 4.7746x; 1.1396x over previous
//
#include <hip/hip_runtime.h>
#include <math.h>
#include <float.h>

typedef __attribute__((ext_vector_type(8))) short short8;
typedef __attribute__((ext_vector_type(4))) float f32x4;

namespace {

constexpr int B = 256;
constexpr int M = 65536;
constexpr int D = 1024;
constexpr float DECAY_EPS = 1e-8f;
constexpr float DECAY_RATE = 0.999f;

constexpr int BN = 64;          // keys per GEMM block
constexpr int BK = 64;          // k per step (two MFMA K-depths)
constexpr int KSTEPS = D / BK;  // 16

constexpr int CHUNKS = 8;           // top-k chunks per row
constexpr int CHUNK = M / CHUNKS;   // 8192
constexpr int NCAND = CHUNKS * 8;   // 64 candidates per row

__device__ inline ushort f2bf(float f) {
  union { float f; unsigned u; } v; v.f = f;
  unsigned r = v.u + 0x7fffu + ((v.u >> 16) & 1u);  // RNE
  return (ushort)(r >> 16);
}

// ---------------------------------------------------------------------------
// Kernel 1: normalize queries, emit bf16 in MFMA A-fragment order:
// qnf[(kt*16 + m_tile)*512 + lane*8 + j] = qn[m_tile*16 + (lane&15)][kt*32 + (lane>>4)*8 + j]
// ---------------------------------------------------------------------------
__global__ void prep_q_kernel(const float* __restrict__ q, ushort* __restrict__ qnf) {
  const int r = blockIdx.x;
  const int t = threadIdx.x;  // 256 threads x float4
  float4 v = reinterpret_cast<const float4*>(q + (size_t)r * D)[t];
  float ss = v.x * v.x + v.y * v.y + v.z * v.z + v.w * v.w;
#pragma unroll
  for (int off = 32; off; off >>= 1) ss += __shfl_down(ss, off, 64);
  __shared__ float red[4];
  if ((t & 63) == 0) red[t >> 6] = ss;
  __syncthreads();
  const float inv = 1.0f / fmaxf(sqrtf(red[0] + red[1] + red[2] + red[3]), DECAY_EPS);
  ushort4 o;
  o.x = f2bf(v.x * inv); o.y = f2bf(v.y * inv);
  o.z = f2bf(v.z * inv); o.w = f2bf(v.w * inv);
  const int k0 = t * 4;
  const int kt = k0 >> 5;
  const int lane_slot = (r & 15) + 16 * ((k0 & 31) >> 3);
  const int j0 = k0 & 7;  // 0 or 4
  *reinterpret_cast<ushort4*>(qnf + (size_t)(kt * 16 + (r >> 4)) * 512 + lane_slot * 8 + j0) = o;
}

// ---------------------------------------------------------------------------
// Kernel 2: bf16-MFMA scores. BM=256 (all rows) x BN=64 keys, BK=64.
// Pipelining: B global loads issued one full step before consumption;
// A fragments prefetched across the barrier (register-dest loads are not
// drained by __syncthreads); per-ks interleaved LDS frag reads.
// ---------------------------------------------------------------------------
__global__ __launch_bounds__(256) void score_gemm_kernel(
    const ushort* __restrict__ qnf, const float* __restrict__ keys,
    const float* __restrict__ importance, const int* __restrict__ atimes,
    const int* __restrict__ acnts, const int* __restrict__ ctime,
    float* __restrict__ scores) {
  __shared__ alignas(16) ushort Bs[2][BN * BK];  // 8 KB per buffer
  __shared__ float cscale[BN];

  const int t = threadIdx.x;
  const int lane = t & 63;
  const int w = t >> 6;
  const int jb = blockIdx.x * BN;

  // staging: thread t stages key row rw (0..63), 16-float chunk cw (0..3)
  const int rw = t >> 2;
  const int cw = t & 3;
  const float4* kp4 = reinterpret_cast<const float4*>(keys + (size_t)(jb + rw) * D) + cw * 4;
  // per step s this thread loads kp4[s*16 + 0..3] (64 floats/row/step)

  // swizzled LDS write offsets (elems): 8 slots of 8 bf16 per row, slot' = slot ^ (row&7)
  const int wo0 = rw * BK + (((2 * cw) ^ (rw & 7)) * 8);
  const int wo1 = rw * BK + (((2 * cw + 1) ^ (rw & 7)) * 8);

  // frag read offsets: row = nf*16+(lane&15), slot = ks*4+(lane>>4)
  int roff[2][4];
#pragma unroll
  for (int ks = 0; ks < 2; ++ks)
#pragma unroll
    for (int nf = 0; nf < 4; ++nf) {
      const int row = nf * 16 + (lane & 15);
      const int slot = ks * 4 + (lane >> 4);
      roff[ks][nf] = row * BK + ((slot ^ (row & 7)) * 8);
    }

  f32x4 acc[4][4];
#pragma unroll
  for (int f = 0; f < 4; ++f)
#pragma unroll
    for (int n = 0; n < 4; ++n) acc[f][n] = (f32x4)(0.0f);

  float kn2 = 0.0f;
  short8 a[2][4];   // A frags for the current step (prefetched)
  float4 bv[4];     // staged B for the next step

  const short8* apbase = reinterpret_cast<const short8*>(qnf);

  auto loadA = [&](int s) {
#pragma unroll
    for (int ks = 0; ks < 2; ++ks)
#pragma unroll
      for (int f = 0; f < 4; ++f)
        a[ks][f] = apbase[(size_t)((2 * s + ks) * 16 + w * 4 + f) * 64 + lane];
  };
  auto loadB = [&](int s) {
#pragma unroll
    for (int i = 0; i < 4; ++i) bv[i] = kp4[s * 16 + i];
  };
  auto stageB = [&](int buf) {
#pragma unroll
    for (int i = 0; i < 4; ++i)
      kn2 += bv[i].x * bv[i].x + bv[i].y * bv[i].y + bv[i].z * bv[i].z + bv[i].w * bv[i].w;
    short8 p0, p1;
    p0[0] = (short)f2bf(bv[0].x); p0[1] = (short)f2bf(bv[0].y);
    p0[2] = (short)f2bf(bv[0].z); p0[3] = (short)f2bf(bv[0].w);
    p0[4] = (short)f2bf(bv[1].x); p0[5] = (short)f2bf(bv[1].y);
    p0[6] = (short)f2bf(bv[1].z); p0[7] = (short)f2bf(bv[1].w);
    p1[0] = (short)f2bf(bv[2].x); p1[1] = (short)f2bf(bv[2].y);
    p1[2] = (short)f2bf(bv[2].z); p1[3] = (short)f2bf(bv[2].w);
    p1[4] = (short)f2bf(bv[3].x); p1[5] = (short)f2bf(bv[3].y);
    p1[6] = (short)f2bf(bv[3].z); p1[7] = (short)f2bf(bv[3].w);
    *reinterpret_cast<short8*>(&Bs[buf][wo0]) = p0;
    *reinterpret_cast<short8*>(&Bs[buf][wo1]) = p1;
  };

  // prologue: stage step 0, prefetch A(0), issue B(1)
  loadB(0);
  stageB(0);
  loadA(0);
  loadB(1);
  __syncthreads();

  for (int s = 0; s < KSTEPS; ++s) {
    const int cur = s & 1;
#pragma unroll
    for (int ks = 0; ks < 2; ++ks) {
      short8 bf[4];
#pragma unroll
      for (int nf = 0; nf < 4; ++nf)
        bf[nf] = *reinterpret_cast<const short8*>(&Bs[cur][roff[ks][nf]]);
#pragma unroll
      for (int f = 0; f < 4; ++f)
#pragma unroll
        for (int nf = 0; nf < 4; ++nf)
          acc[f][nf] = __builtin_amdgcn_mfma_f32_16x16x32_bf16(a[ks][f], bf[nf], acc[f][nf], 0, 0, 0);
    }
    if (s + 1 < KSTEPS) {
      loadA(s + 1);        // reuses a[] regs; in flight across the barrier
      stageB(cur ^ 1);     // consumes bv (issued one full step ago)
      if (s + 2 < KSTEPS) loadB(s + 2);  // issue next B into bv
    }
    __syncthreads();
  }

  // key norm^2: reduce over the 4 staging threads of row rw (consecutive lanes)
  kn2 += __shfl_xor(kn2, 1, 64);
  kn2 += __shfl_xor(kn2, 2, 64);
  if (cw == 0) {
    const int j = jb + rw;
    const float dt = (float)(ctime[0] - atimes[j]);
    const float mult = powf(DECAY_RATE, dt) * importance[j] * log1pf((float)acnts[j]);
    cscale[rw] = mult / fmaxf(sqrtf(kn2), DECAY_EPS);
  }
  __syncthreads();

  // epilogue: C/D layout col=lane&15, row=(lane>>4)*4+reg
#pragma unroll
  for (int f = 0; f < 4; ++f) {
    const int row0 = (w * 4 + f) * 16 + ((lane >> 4) << 2);
#pragma unroll
    for (int nf = 0; nf < 4; ++nf) {
      const int col = nf * 16 + (lane & 15);
      const float cs = cscale[col];
#pragma unroll
      for (int rr = 0; rr < 4; ++rr)
        scores[(size_t)(row0 + rr) * M + jb + col] = acc[f][nf][rr] * cs;
    }
  }
}

// ---------------------------------------------------------------------------
// Kernel 3 (stage A): per (row, chunk) top-8 indices. Branch-free insertion,
// all static indexing (registers, NOT scratch).
// ---------------------------------------------------------------------------
__global__ __launch_bounds__(256) void topk_partial_kernel(
    const float* __restrict__ scores, int* __restrict__ cand_i) {
  const int b = blockIdx.y;
  const int c = blockIdx.x;
  const int t = threadIdx.x;
  const int lane = t & 63, w = t >> 6;
  const float4* base4 = reinterpret_cast<const float4*>(scores + (size_t)b * M + (size_t)c * CHUNK);

  float s8[8];
  int i8[8];
#pragma unroll
  for (int i = 0; i < 8; ++i) { s8[i] = -FLT_MAX; i8[i] = 0; }

  auto ins = [&](float x, int j) {
    if (x > s8[0]) {
#pragma unroll
      for (int i = 0; i < 8; ++i) {
        const bool up = (i < 7) && (x > s8[i + 1]);
        const float ks = (x > s8[i]) ? x : s8[i];
        const int ki = (x > s8[i]) ? j : i8[i];
        s8[i] = up ? s8[i + 1] : ks;
        i8[i] = up ? i8[i + 1] : ki;
      }
    }
  };

  const int jbase = c * CHUNK;
  for (int it = 0; it < CHUNK / (256 * 4); ++it) {  // 8 iters
    const int slot = it * 256 + t;
    const float4 v = base4[slot];
    const int j0 = jbase + slot * 4;
    ins(v.x, j0 + 0);
    ins(v.y, j0 + 1);
    ins(v.z, j0 + 2);
    ins(v.w, j0 + 3);
  }

  __shared__ float ls[2048];
  __shared__ int li[2048];
#pragma unroll
  for (int i = 0; i < 8; ++i) { ls[t * 8 + i] = s8[i]; li[t * 8 + i] = i8[i]; }
  __syncthreads();

  __shared__ float rs4[4];
  __shared__ int rp4[4];
  for (int r = 0; r < 8; ++r) {
    float ms = -FLT_MAX;
    int mp = 0;
#pragma unroll
    for (int i = 0; i < 8; ++i) {
      const float v = ls[i * 256 + t];
      if (v > ms) { ms = v; mp = i * 256 + t; }
    }
#pragma unroll
    for (int off = 32; off; off >>= 1) {
      const float ov = __shfl_xor(ms, off, 64);
      const int op = __shfl_xor(mp, off, 64);
      if (ov > ms) { ms = ov; mp = op; }
    }
    if (lane == 0) { rs4[w] = ms; rp4[w] = mp; }
    __syncthreads();
    if (t == 0) {
      float bs = -FLT_MAX;
      int bp = 0;
#pragma unroll
      for (int i = 0; i < 4; ++i)
        if (rs4[i] > bs) { bs = rs4[i]; bp = rp4[i]; }
      cand_i[((size_t)b * CHUNKS + c) * 8 + r] = li[bp];
      ls[bp] = -FLT_MAX;
    }
    __syncthreads();
  }
}

// ---------------------------------------------------------------------------
// Kernel 4 (stage B): exact fp32 rescore of 64 candidates, top-8, softmax,
// weighted value gather. One block (512 thr = 8 waves) per row.
// ---------------------------------------------------------------------------
__global__ __launch_bounds__(512) void rescore_kernel(
    const int* __restrict__ cand_i, const float* __restrict__ query,
    const float* __restrict__ keys, const float* __restrict__ values,
    const float* __restrict__ importance, const int* __restrict__ atimes,
    const int* __restrict__ acnts, const int* __restrict__ ctime,
    float* __restrict__ outc, float* __restrict__ conf) {
  const int b = blockIdx.x;
  const int t = threadIdx.x;
  const int lane = t & 63, w = t >> 6;

  const float4* qv4 = reinterpret_cast<const float4*>(query + (size_t)b * D + lane * 16);
  float4 q0 = qv4[0], q1 = qv4[1], q2 = qv4[2], q3 = qv4[3];
  float ssq = q0.x * q0.x + q0.y * q0.y + q0.z * q0.z + q0.w * q0.w
            + q1.x * q1.x + q1.y * q1.y + q1.z * q1.z + q1.w * q1.w
            + q2.x * q2.x + q2.y * q2.y + q2.z * q2.z + q2.w * q2.w
            + q3.x * q3.x + q3.y * q3.y + q3.z * q3.z + q3.w * q3.w;
#pragma unroll
  for (int off = 32; off; off >>= 1) ssq += __shfl_xor(ssq, off, 64);
  const float qdn = fmaxf(sqrtf(ssq), DECAY_EPS);
  const int ct = ctime[0];

  __shared__ float sc[NCAND];
  __shared__ int sidx[NCAND];

  for (int u = 0; u < 8; ++u) {
    const int c = w * 8 + u;
    const int j = cand_i[(size_t)b * NCAND + c];
    const float4* kv4 = reinterpret_cast<const float4*>(keys + (size_t)j * D + lane * 16);
    const float4 k0 = kv4[0], k1 = kv4[1], k2 = kv4[2], k3 = kv4[3];
    float dd = q0.x * k0.x + q0.y * k0.y + q0.z * k0.z + q0.w * k0.w
             + q1.x * k1.x + q1.y * k1.y + q1.z * k1.z + q1.w * k1.w
             + q2.x * k2.x + q2.y * k2.y + q2.z * k2.z + q2.w * k2.w
             + q3.x * k3.x + q3.y * k3.y + q3.z * k3.z + q3.w * k3.w;
    float nn = k0.x * k0.x + k0.y * k0.y + k0.z * k0.z + k0.w * k0.w
             + k1.x * k1.x + k1.y * k1.y + k1.z * k1.z + k1.w * k1.w
             + k2.x * k2.x + k2.y * k2.y + k2.z * k2.z + k2.w * k2.w
             + k3.x * k3.x + k3.y * k3.y + k3.z * k3.z + k3.w * k3.w;
#pragma unroll
    for (int off = 32; off; off >>= 1) {
      dd += __shfl_xor(dd, off, 64);
      nn += __shfl_xor(nn, off, 64);
    }
    if (lane == 0) {
      const float dtv = (float)(ct - atimes[j]);
      const float mult = powf(DECAY_RATE, dtv) * importance[j] * log1pf((float)acnts[j]);
      sc[c] = dd / (qdn * fmaxf(sqrtf(nn), DECAY_EPS)) * mult;
      sidx[c] = j;
    }
  }
  __syncthreads();

  __shared__ float w8s[8];
  __shared__ int g8[8];
  __shared__ float confv;
  __shared__ float tls[8];
  __shared__ int tli[8];
  if (w == 0) {
    float myv = sc[lane];
    for (int r = 0; r < 8; ++r) {
      float m = myv;
      int mi = lane;
#pragma unroll
      for (int off = 32; off; off >>= 1) {
        const float ov = __shfl_xor(m, off, 64);
        const int oi = __shfl_xor(mi, off, 64);
        if (ov > m || (ov == m && oi < mi)) { m = ov; mi = oi; }
      }
      if (lane == 0) { tls[r] = m; tli[r] = mi; }
      if (lane == mi) myv = -FLT_MAX;
    }
    if (lane == 0) {
      const float mx = tls[0];
      float e[8];
      float z = 0.0f;
#pragma unroll
      for (int r = 0; r < 8; ++r) { e[r] = expf(tls[r] - mx); z += e[r]; }
      const float invz = 1.0f / z;
#pragma unroll
      for (int r = 0; r < 8; ++r) { w8s[r] = e[r] * invz; g8[r] = sidx[tli[r]]; }
      confv = w8s[0];
    }
  }
  __syncthreads();

  float2 acc = make_float2(0.0f, 0.0f);
#pragma unroll
  for (int k = 0; k < 8; ++k) {
    const float wk = w8s[k];
    const float2 v = *reinterpret_cast<const float2*>(values + (size_t)g8[k] * D + 2 * t);
    acc.x = fmaf(wk, v.x, acc.x);
    acc.y = fmaf(wk, v.y, acc.y);
  }
  *reinterpret_cast<float2*>(outc + (size_t)b * D + 2 * t) = acc;
  if (t == 0) conf[b] = confv;
}

}  // namespace

extern "C" void kernel_launch(void* const* d_in, const int* in_sizes, int n_in,
                              void* d_out, int out_size, void* d_ws, size_t ws_size,
                              hipStream_t stream) {
  const float* query = (const float*)d_in[0];
  const float* keys = (const float*)d_in[1];
  const float* values = (const float*)d_in[2];
  const float* importance = (const float*)d_in[3];
  const int* atimes = (const int*)d_in[4];
  const int* acnts = (const int*)d_in[5];
  const int* ctime = (const int*)d_in[6];

  float* out = (float*)d_out;  // combined [B*D] then confidence [B]
  ushort* qnf = (ushort*)d_ws;                                             // 512 KB
  float* scores = (float*)((char*)d_ws + (size_t)B * D * sizeof(ushort));  // 64 MB
  int* cand = (int*)(scores + (size_t)B * M);                              // 64 KB

  prep_q_kernel<<<B, 256, 0, stream>>>(query, qnf);
  score_gemm_kernel<<<M / BN, 256, 0, stream>>>(qnf, keys, importance, atimes,
                                                acnts, ctime, scores);
  dim3 gA(CHUNKS, B);
  topk_partial_kernel<<<gA, 256, 0, stream>>>(scores, cand);
  rescore_kernel<<<B, 512, 0, stream>>>(cand, query, keys, values, importance,
                                        atimes, acnts, ctime, out, out + (size_t)B * D);
}